// Round 2
// baseline (1620.771 us; speedup 1.0000x reference)
//
#include <hip/hip_runtime.h>

// Sizes for this problem instance
#define DD   160      // D = T
#define KKE  589      // estimator columns
#define RR   8        // rank
#define NNX  32768    // N = C*H*W
#define NB   8        // batch (B*S)
#define EPSN 1e-6f

// ---------------------------------------------------------------------------
// Build E [D,K] and ET [K,D]. grid 160 blocks (one per t), 256 threads.
__global__ __launch_bounds__(256) void k_build(float* __restrict__ E, float* __restrict__ ET) {
    const int t = blockIdx.x;
    for (int j = threadIdx.x; j < KKE; j += 256) {
        float val;
        if (j == 588) {
            val = 1.f;
        } else {
            int n; float s2x4;
            if (j < 160)      { n = j;           s2x4 = 144.f;  }   // sig 6
            else if (j < 320) { n = j - 160;     s2x4 = 256.f;  }   // sig 8
            else if (j < 400) { n = 2*(j - 320); s2x4 = 576.f;  }   // sig 12
            else if (j < 480) { n = 2*(j - 400); s2x4 = 900.f;  }   // sig 15
            else if (j < 534) { n = 3*(j - 480); s2x4 = 1296.f; }   // sig 18
            else              { n = 3*(j - 534); s2x4 = 2304.f; }   // sig 24
            float d = (float)(t - n);
            val = expf(-(d * d) / s2x4);
        }
        E[t*KKE + j]  = val;
        ET[j*DD + t]  = val;
    }
}

// ---------------------------------------------------------------------------
// L2-normalize bases columns (dim=k). grid 64 = (b,r), 256 threads.
// Also zeroes ebt (accumulated later by k_eb).
__global__ __launch_bounds__(256) void k_norm(const float* __restrict__ bsrc,
                                              float* __restrict__ bdst,
                                              float* __restrict__ ebt) {
    __shared__ float red[4];
    const int tid = threadIdx.x;
    const int b = blockIdx.x >> 3;
    const int r = blockIdx.x & 7;
    if (r == 0 && tid < 64) ebt[b*64 + tid] = 0.f;
    const int k0 = tid, k1 = tid + 256, k2 = tid + 512;
    float v0 = bsrc[(b*KKE + k0)*RR + r];
    float v1 = bsrc[(b*KKE + k1)*RR + r];
    float v2 = (k2 < KKE) ? bsrc[(b*KKE + k2)*RR + r] : 0.f;
    float ss = v0*v0 + v1*v1 + v2*v2;
    #pragma unroll
    for (int off = 32; off; off >>= 1) ss += __shfl_xor(ss, off);
    if ((tid & 63) == 0) red[tid >> 6] = ss;
    __syncthreads();
    const float tot = red[0] + red[1] + red[2] + red[3];
    const float scale = 1.f / fmaxf(sqrtf(tot), 1e-12f);
    bdst[(b*KKE + k0)*RR + r] = v0*scale;
    bdst[(b*KKE + k1)*RR + r] = v1*scale;
    if (k2 < KKE) bdst[(b*KKE + k2)*RR + r] = v2*scale;
}

// ---------------------------------------------------------------------------
// Eb[b,d,r] = sum_k E[d,k]*bases[b,k,r]; accumulates ebt[b,r,s] = Eb^T Eb.
// Also zeroes xc / ctc for the NEXT step's accumulation (safe: previous
// consumers ran in earlier launches).
// grid (5 d-chunks, 8 b), 256 threads = (32 d × 8 r).
__global__ __launch_bounds__(256) void k_eb(const float* __restrict__ ET,
                                            const float* __restrict__ bases,
                                            float* __restrict__ Eb,
                                            float* __restrict__ ebt,
                                            float* __restrict__ xc,
                                            float* __restrict__ ctc) {
    __shared__ float bl[KKE*RR];      // 18.8 KB
    __shared__ float ebl[32*RR];
    const int tid = threadIdx.x;
    const int dc = blockIdx.x;        // 0..4
    const int b  = blockIdx.y;

    // zero accumulators for next step
    xc[b*DD*RR + dc*256 + tid] = 0.f;
    if (dc == 0 && tid < 64) ctc[b*64 + tid] = 0.f;

    // stage bases[b] (4712 floats = 1178 float4)
    const float4* bsrc4 = (const float4*)(bases + (size_t)b*KKE*RR);
    for (int i = tid; i < (KKE*RR)/4; i += 256) ((float4*)bl)[i] = bsrc4[i];
    __syncthreads();

    const int dl = tid >> 3, r = tid & 7;
    const int d = dc*32 + dl;
    float acc = 0.f;
    #pragma unroll 4
    for (int k = 0; k < KKE; ++k)
        acc += ET[k*DD + d] * bl[k*8 + r];
    Eb[b*DD*RR + d*RR + r] = acc;
    ebl[dl*8 + r] = acc;
    __syncthreads();
    if (tid < 64) {
        const int r2 = tid >> 3, s2 = tid & 7;
        float p = 0.f;
        #pragma unroll
        for (int i = 0; i < 32; ++i) p += ebl[i*8 + r2] * ebl[i*8 + s2];
        atomicAdd(&ebt[b*64 + r2*8 + s2], p);
    }
}

// ---------------------------------------------------------------------------
// Fused num_c + coef multiplicative update + ctc accumulation.
// grid (64, 8), 256 threads, 2 columns/thread. No LDS for data; Eb/ebt read
// with uniform addresses (scalar loads).
template <bool FIRST>
__global__ __launch_bounds__(256) void k_coef(const float* __restrict__ x,
                                              const float* __restrict__ Eb,
                                              const float* __restrict__ ebt,
                                              float* __restrict__ coef,
                                              float* __restrict__ ctc) {
    const int tid = threadIdx.x;
    const int b = blockIdx.y;
    const int n0 = blockIdx.x*512 + tid*2;
    const float* __restrict__ ebg = Eb + b*DD*RR;
    const float* __restrict__ xp  = x + (size_t)b*DD*NNX + n0;

    float a0[8] = {0,0,0,0,0,0,0,0}, a1[8] = {0,0,0,0,0,0,0,0};
    #pragma unroll 2
    for (int d = 0; d < DD; ++d) {
        const float2 xv = *(const float2*)(xp + (size_t)d*NNX);
        float e[8];
        *(float4*)&e[0] = *(const float4*)(ebg + d*RR);
        *(float4*)&e[4] = *(const float4*)(ebg + d*RR + 4);
        #pragma unroll
        for (int r = 0; r < 8; ++r) { a0[r] += xv.x*e[r]; a1[r] += xv.y*e[r]; }
    }

    float c0[8], c1[8];
    if (FIRST) {
        float m0 = a0[0], m1 = a1[0];
        #pragma unroll
        for (int r = 1; r < 8; ++r) { m0 = fmaxf(m0, a0[r]); m1 = fmaxf(m1, a1[r]); }
        float s0 = 0.f, s1 = 0.f;
        #pragma unroll
        for (int r = 0; r < 8; ++r) { c0[r] = expf(a0[r]-m0); s0 += c0[r];
                                      c1[r] = expf(a1[r]-m1); s1 += c1[r]; }
        const float i0 = 1.f/s0, i1 = 1.f/s1;
        #pragma unroll
        for (int r = 0; r < 8; ++r) { c0[r] *= i0; c1[r] *= i1; }
    } else {
        float* cp = coef + ((size_t)b*NNX + n0)*RR;
        *(float4*)&c0[0] = *(const float4*)(cp);
        *(float4*)&c0[4] = *(const float4*)(cp + 4);
        *(float4*)&c1[0] = *(const float4*)(cp + 8);
        *(float4*)&c1[4] = *(const float4*)(cp + 12);
    }

    // den = cold · ebteb   (ebteb symmetric)
    const float* __restrict__ ebtp = ebt + b*64;
    float d0[8] = {0,0,0,0,0,0,0,0}, d1[8] = {0,0,0,0,0,0,0,0};
    #pragma unroll
    for (int s = 0; s < 8; ++s) {
        float e[8];
        *(float4*)&e[0] = *(const float4*)(ebtp + s*8);
        *(float4*)&e[4] = *(const float4*)(ebtp + s*8 + 4);
        #pragma unroll
        for (int r = 0; r < 8; ++r) { d0[r] += c0[s]*e[r]; d1[r] += c1[s]*e[r]; }
    }
    #pragma unroll
    for (int r = 0; r < 8; ++r) {
        c0[r] = c0[r]*a0[r]/(d0[r] + EPSN);
        c1[r] = c1[r]*a1[r]/(d1[r] + EPSN);
    }
    {
        float* cp = coef + ((size_t)b*NNX + n0)*RR;
        *(float4*)(cp)      = *(float4*)&c0[0];
        *(float4*)(cp + 4)  = *(float4*)&c0[4];
        *(float4*)(cp + 8)  = *(float4*)&c1[0];
        *(float4*)(cp + 12) = *(float4*)&c1[4];
    }

    // ctc (upper triangle, 36 values), wave-reduce then atomics
    float ctv[36];
    #pragma unroll
    for (int r = 0; r < 8; ++r) {
        #pragma unroll
        for (int s = r; s < 8; ++s)
            ctv[r*8 + s - (r*(r+1))/2] = c0[r]*c0[s] + c1[r]*c1[s];
    }
    #pragma unroll
    for (int off = 32; off; off >>= 1) {
        #pragma unroll
        for (int v = 0; v < 36; ++v) ctv[v] += __shfl_xor(ctv[v], off);
    }
    if ((tid & 63) == 0) {
        #pragma unroll
        for (int r = 0; r < 8; ++r) {
            #pragma unroll
            for (int s = r; s < 8; ++s) {
                const float v = ctv[r*8 + s - (r*(r+1))/2];
                atomicAdd(&ctc[b*64 + r*8 + s], v);
                if (s != r) atomicAdd(&ctc[b*64 + s*8 + r], v);
            }
        }
    }
}

// ---------------------------------------------------------------------------
// xc[b,d,r] += sum_n x[b,d,n]*coef[b,n,r].  grid (64, 8), 320 threads =
// (40 d-quads × 8 n-stripes), n-chunk 512. Also zeroes ebt for next k_eb.
__global__ __launch_bounds__(320) void k_xct(const float* __restrict__ x,
                                             const float* __restrict__ coef,
                                             float* __restrict__ xc,
                                             float* __restrict__ ebt) {
    __shared__ float red[320*33];
    const int tid = threadIdx.x;
    const int b  = blockIdx.y;
    const int n0 = blockIdx.x*512;
    if (blockIdx.x == 0 && tid < 64) ebt[b*64 + tid] = 0.f;

    const int dq = tid >> 3;   // 0..39
    const int st = tid & 7;
    const float* __restrict__ xb = x + (size_t)b*DD*NNX;
    const float* __restrict__ cb = coef + (size_t)b*NNX*RR;

    float acc[4][8] = {{0}};
    for (int g = 0; g < 16; ++g) {
        const int n = n0 + g*32 + st*4;
        float c[4][8];
        #pragma unroll
        for (int j = 0; j < 4; ++j) {
            *(float4*)&c[j][0] = *(const float4*)(cb + (size_t)(n+j)*RR);
            *(float4*)&c[j][4] = *(const float4*)(cb + (size_t)(n+j)*RR + 4);
        }
        #pragma unroll
        for (int i = 0; i < 4; ++i) {
            float xv[4];
            *(float4*)&xv[0] = *(const float4*)(xb + (size_t)(dq*4+i)*NNX + n);
            #pragma unroll
            for (int j = 0; j < 4; ++j) {
                #pragma unroll
                for (int r = 0; r < 8; ++r) acc[i][r] += xv[j]*c[j][r];
            }
        }
    }
    // cross-stripe reduce via LDS (stride 33 → conflict-free)
    #pragma unroll
    for (int v = 0; v < 32; ++v) red[tid*33 + v] = acc[v>>3][v&7];
    __syncthreads();
    {
        const int dqr = tid >> 3, r = tid & 7;   // all 320 threads
        float s0=0.f, s1=0.f, s2=0.f, s3=0.f;
        #pragma unroll
        for (int s = 0; s < 8; ++s) {
            const float* rp = &red[(dqr*8 + s)*33];
            s0 += rp[0*8 + r]; s1 += rp[1*8 + r]; s2 += rp[2*8 + r]; s3 += rp[3*8 + r];
        }
        float* xcp = &xc[b*DD*RR + (dqr*4)*RR + r];
        atomicAdd(xcp + 0,  s0);
        atomicAdd(xcp + 8,  s1);
        atomicAdd(xcp + 16, s2);
        atomicAdd(xcp + 24, s3);
    }
}

// ---------------------------------------------------------------------------
// Bases multiplicative update (in place).  tmp = Eb_old*ctc.
// grid (3, 64): blockIdx.x = k-chunk, blockIdx.y = (b,r). 256 threads.
__global__ __launch_bounds__(256) void k_bupd(const float* __restrict__ E,
                                              const float* __restrict__ Eb,
                                              float* __restrict__ bases,
                                              const float* __restrict__ xc,
                                              const float* __restrict__ ctc) {
    __shared__ float xcl[DD];
    __shared__ float tmp[DD];
    __shared__ float ctcc[8];
    const int tid = threadIdx.x;
    const int b = blockIdx.y >> 3;
    const int r = blockIdx.y & 7;
    if (tid < 8)  ctcc[tid] = ctc[b*64 + tid*8 + r];
    if (tid < DD) xcl[tid] = xc[b*DD*RR + tid*RR + r];
    __syncthreads();
    if (tid < DD) {
        float a = 0.f;
        #pragma unroll
        for (int s = 0; s < 8; ++s) a += Eb[b*DD*RR + tid*RR + s] * ctcc[s];
        tmp[tid] = a;
    }
    __syncthreads();
    const int k = blockIdx.x*256 + tid;
    if (k < KKE) {
        float nb = 0.f, db = 0.f;
        #pragma unroll 4
        for (int d = 0; d < DD; ++d) {
            const float e = E[d*KKE + k];
            nb += e * xcl[d];
            db += e * tmp[d];
        }
        const float bo = bases[(b*KKE + k)*RR + r];
        bases[(b*KKE + k)*RR + r] = bo * nb / (db + EPSN);
    }
}

// ---------------------------------------------------------------------------
// Final compute_coef + reconstruction. grid (64, 8), 256 threads, 2 cols.
__global__ __launch_bounds__(256) void k_final(const float* __restrict__ x,
                                               const float* __restrict__ Eb,
                                               const float* __restrict__ ebt,
                                               const float* __restrict__ coef,
                                               float* __restrict__ out) {
    const int tid = threadIdx.x;
    const int b = blockIdx.y;
    const int n0 = blockIdx.x*512 + tid*2;
    const float* __restrict__ ebg = Eb + b*DD*RR;
    const float* __restrict__ xp  = x + (size_t)b*DD*NNX + n0;

    float a0[8] = {0,0,0,0,0,0,0,0}, a1[8] = {0,0,0,0,0,0,0,0};
    #pragma unroll 2
    for (int d = 0; d < DD; ++d) {
        const float2 xv = *(const float2*)(xp + (size_t)d*NNX);
        float e[8];
        *(float4*)&e[0] = *(const float4*)(ebg + d*RR);
        *(float4*)&e[4] = *(const float4*)(ebg + d*RR + 4);
        #pragma unroll
        for (int r = 0; r < 8; ++r) { a0[r] += xv.x*e[r]; a1[r] += xv.y*e[r]; }
    }
    float c0[8], c1[8];
    {
        const float* cp = coef + ((size_t)b*NNX + n0)*RR;
        *(float4*)&c0[0] = *(const float4*)(cp);
        *(float4*)&c0[4] = *(const float4*)(cp + 4);
        *(float4*)&c1[0] = *(const float4*)(cp + 8);
        *(float4*)&c1[4] = *(const float4*)(cp + 12);
    }
    const float* __restrict__ ebtp = ebt + b*64;
    float d0[8] = {0,0,0,0,0,0,0,0}, d1[8] = {0,0,0,0,0,0,0,0};
    #pragma unroll
    for (int s = 0; s < 8; ++s) {
        float e[8];
        *(float4*)&e[0] = *(const float4*)(ebtp + s*8);
        *(float4*)&e[4] = *(const float4*)(ebtp + s*8 + 4);
        #pragma unroll
        for (int r = 0; r < 8; ++r) { d0[r] += c0[s]*e[r]; d1[r] += c1[s]*e[r]; }
    }
    #pragma unroll
    for (int r = 0; r < 8; ++r) {
        c0[r] = c0[r]*a0[r]/(d0[r] + EPSN);
        c1[r] = c1[r]*a1[r]/(d1[r] + EPSN);
    }
    float* op = (float*)out + (size_t)b*DD*NNX + n0;
    #pragma unroll 2
    for (int d = 0; d < DD; ++d) {
        float e[8];
        *(float4*)&e[0] = *(const float4*)(ebg + d*RR);
        *(float4*)&e[4] = *(const float4*)(ebg + d*RR + 4);
        float o0 = 0.f, o1 = 0.f;
        #pragma unroll
        for (int r = 0; r < 8; ++r) { o0 += e[r]*c0[r]; o1 += e[r]*c1[r]; }
        *(float2*)(op + (size_t)d*NNX) = make_float2(o0, o1);
    }
}

// ---------------------------------------------------------------------------
extern "C" void kernel_launch(void* const* d_in, const int* in_sizes, int n_in,
                              void* d_out, int out_size, void* d_ws, size_t ws_size,
                              hipStream_t stream) {
    const float* x     = (const float*)d_in[0];
    const float* binit = (const float*)d_in[1];
    float* out = (float*)d_out;

    float* w      = (float*)d_ws;
    float* E      = w;                          // 94240
    float* ET     = E      + DD*KKE;            // 94240
    float* bases  = ET     + DD*KKE;            // 37696
    float* Eb     = bases  + NB*KKE*RR;         // 10240
    float* ebt    = Eb     + NB*DD*RR;          // 512
    float* coef   = ebt    + NB*64;             // 2097152
    float* xc     = coef   + (size_t)NB*NNX*RR; // 10240
    float* ctc    = xc     + NB*DD*RR;          // 512

    const dim3 g_eb(5, 8), g_cf(64, 8), g_xc(64, 8), g_bu(3, 64), g_fin(64, 8);

    k_build<<<160, 256, 0, stream>>>(E, ET);
    k_norm<<<64, 256, 0, stream>>>(binit, bases, ebt);
    k_eb<<<g_eb, 256, 0, stream>>>(ET, bases, Eb, ebt, xc, ctc);

    // step 1 (softmax fused)
    k_coef<true><<<g_cf, 256, 0, stream>>>(x, Eb, ebt, coef, ctc);
    k_xct<<<g_xc, 320, 0, stream>>>(x, coef, xc, ebt);
    k_bupd<<<g_bu, 256, 0, stream>>>(E, Eb, bases, xc, ctc);
    k_eb<<<g_eb, 256, 0, stream>>>(ET, bases, Eb, ebt, xc, ctc);
    // step 2
    k_coef<false><<<g_cf, 256, 0, stream>>>(x, Eb, ebt, coef, ctc);
    k_xct<<<g_xc, 320, 0, stream>>>(x, coef, xc, ebt);
    k_bupd<<<g_bu, 256, 0, stream>>>(E, Eb, bases, xc, ctc);
    k_eb<<<g_eb, 256, 0, stream>>>(ET, bases, Eb, ebt, xc, ctc);
    // step 3
    k_coef<false><<<g_cf, 256, 0, stream>>>(x, Eb, ebt, coef, ctc);
    k_xct<<<g_xc, 320, 0, stream>>>(x, coef, xc, ebt);
    k_bupd<<<g_bu, 256, 0, stream>>>(E, Eb, bases, xc, ctc);
    k_eb<<<g_eb, 256, 0, stream>>>(ET, bases, Eb, ebt, xc, ctc);
    // step 4
    k_coef<false><<<g_cf, 256, 0, stream>>>(x, Eb, ebt, coef, ctc);
    k_xct<<<g_xc, 320, 0, stream>>>(x, coef, xc, ebt);
    k_bupd<<<g_bu, 256, 0, stream>>>(E, Eb, bases, xc, ctc);
    k_eb<<<g_eb, 256, 0, stream>>>(ET, bases, Eb, ebt, xc, ctc);
    // compute_coef + reconstruction
    k_final<<<g_fin, 256, 0, stream>>>(x, Eb, ebt, coef, out);
}